// Round 14
// baseline (293.104 us; speedup 1.0000x reference)
//
#include <hip/hip_runtime.h>
#include <stdint.h>

// F=16, N=8192, D=64, K=512. fp32 in/out. Bit-exact numpy-fp32 emulation (R7/R12-proven):
// dot = sequential-d fl(acc+fl(x*w)); xsq = pairwise-8 tree; wsq = sequential-d;
// dist = fl(fl(xsq - fl(2*dot)) + wsq); first-index argmin; STE fl(x + fl(q-x)).
// R14 = R12 with code-pair packing: v2f accumulator (codes 2j,2j+1), pk_mul+pk_add
// per d — per-half rounding sequence identical to R12's scalar chain. W rows
// pair-interleaved (528B): [ (w2j[d],w2j1[d]) d=0..63, wsq2j, wsq2j1, pad ].
// SGPR broadcast via s_load (R10-proven); two load batches per pair (SGPR budget).
#define F_ 16
#define N_ 8192
#define D_ 64
#define K_ 512
#define KP (K_ / 2)                  // 256 code pairs
#define PROW 132                     // floats per pair-row (528 B, 16B-aligned)

typedef __attribute__((ext_vector_type(16))) float f16v;
typedef __attribute__((ext_vector_type(2)))  float v2f;
typedef unsigned long long u64;

__device__ __forceinline__ u64 umin64(u64 a, u64 b) { return a < b ? a : b; }

// -------- prep: pair-interleaved transpose + embedded seq-d wsq --------
__global__ __launch_bounds__(256) void vq_prep(const float* __restrict__ w,
                                               float* __restrict__ wt) {
    #pragma clang fp contract(off)
    int i = blockIdx.x * 256 + threadIdx.x;   // one thread per (f,k)
    int f = i >> 9;
    int k = i & (K_ - 1);
    const float* wf = w + (size_t)f * D_ * K_;
    float* dst = wt + ((size_t)f * KP + (k >> 1)) * PROW + (k & 1);
    float s = 0.f;
    #pragma unroll 8
    for (int d = 0; d < D_; ++d) {
        float v = wf[(size_t)d * K_ + k];     // coalesced over k
        dst[2 * d] = v;
        s = __fadd_rn(s, __fmul_rn(v, v));    // numpy seq-d reduce (R7-verified)
    }
    dst[2 * D_] = s;                          // wsq at row[128 + (k&1)]
}

// -------- main: block = 64 points x 4 K-quarters; lane = point --------
__global__ __launch_bounds__(256, 3) void vq_main(const float* __restrict__ x,
                                                  const float* __restrict__ wt,
                                                  float* __restrict__ out,
                                                  double* __restrict__ lacc) {
    #pragma clang fp contract(off)
    __shared__ u64 keys[4][64];

    const int tid  = threadIdx.x;
    const int kq   = tid >> 6;                       // K-quarter 0..3
    const int lane = tid & 63;
    const int point = blockIdx.x * 64 + lane;
    const int f     = blockIdx.x >> 7;               // 128 blocks per f; uniform

    // x -> splatted VGPR pairs: xpk[d] = (x[d], x[d]); .x used for xsq/epilogue
    v2f xpk[D_];
    {
        const float4* xv = (const float4*)(x + (size_t)point * D_);
        #pragma unroll
        for (int i = 0; i < D_ / 4; ++i) {
            float4 u = xv[i];
            xpk[4*i+0] = (v2f){u.x, u.x}; xpk[4*i+1] = (v2f){u.y, u.y};
            xpk[4*i+2] = (v2f){u.z, u.z}; xpk[4*i+3] = (v2f){u.w, u.w};
        }
    }

    // xsq: numpy pairwise-8 tree (R7-verified bit-exact)
    float xsq;
    {
        float r[8];
        #pragma unroll
        for (int j = 0; j < 8; ++j) r[j] = __fmul_rn(xpk[j].x, xpk[j].x);
        #pragma unroll
        for (int i = 8; i < 64; i += 8)
            #pragma unroll
            for (int j = 0; j < 8; ++j)
                r[j] = __fadd_rn(r[j], __fmul_rn(xpk[i+j].x, xpk[i+j].x));
        float c01 = __fadd_rn(r[0], r[1]), c23 = __fadd_rn(r[2], r[3]);
        float c45 = __fadd_rn(r[4], r[5]), c67 = __fadd_rn(r[6], r[7]);
        xsq = __fadd_rn(__fadd_rn(c01, c23), __fadd_rn(c45, c67));
    }

    const float* wtf = wt + (size_t)f * KP * PROW;
    const int p0 = kq << 6;                          // 64 pair-rows per quarter

    // Wave-uniform byte base, laundered to SGPRs (R10-proven pattern).
    uint64_t a = (uint64_t)(wtf + (size_t)p0 * PROW);
    uint32_t alo = __builtin_amdgcn_readfirstlane((uint32_t)a);
    uint32_t ahi = __builtin_amdgcn_readfirstlane((uint32_t)(a >> 32));
    const uint64_t ubase = ((uint64_t)ahi << 32) | alo;

    u64 kmin = ~0ull;

    #pragma clang loop unroll(disable)
    for (int pp = 0; pp < 64; ++pp) {
        uint64_t ua = ubase + (uint64_t)pp * (PROW * 4);
        v2f acc = (v2f){0.f, 0.f};

        // batch 1: floats 0..63 = d 0..31
        {
            f16v wa, wb, wc, wd;
            asm("s_load_dwordx16 %0, %4, 0x0\n\t"
                "s_load_dwordx16 %1, %4, 0x40\n\t"
                "s_load_dwordx16 %2, %4, 0x80\n\t"
                "s_load_dwordx16 %3, %4, 0xc0\n\t"
                "s_waitcnt lgkmcnt(0)"
                : "=s"(wa), "=s"(wb), "=s"(wc), "=s"(wd)
                : "s"(ua));
            #pragma unroll
            for (int i = 0; i < 8; ++i) {
                v2f wp = (v2f){wa[2*i], wa[2*i+1]};       // SGPR pair (even-aligned)
                acc = acc + xpk[i] * wp;                  // pk_mul, pk_add: exact per half
            }
            #pragma unroll
            for (int i = 0; i < 8; ++i) {
                v2f wp = (v2f){wb[2*i], wb[2*i+1]};
                acc = acc + xpk[8 + i] * wp;
            }
            #pragma unroll
            for (int i = 0; i < 8; ++i) {
                v2f wp = (v2f){wc[2*i], wc[2*i+1]};
                acc = acc + xpk[16 + i] * wp;
            }
            #pragma unroll
            for (int i = 0; i < 8; ++i) {
                v2f wp = (v2f){wd[2*i], wd[2*i+1]};
                acc = acc + xpk[24 + i] * wp;
            }
        }
        // batch 2: floats 64..127 = d 32..63, + wsq pair at 0x200
        float s0, s1;
        {
            f16v we, wf_, wg, wh;
            v2f wq;
            asm("s_load_dwordx16 %0, %5, 0x100\n\t"
                "s_load_dwordx16 %1, %5, 0x140\n\t"
                "s_load_dwordx16 %2, %5, 0x180\n\t"
                "s_load_dwordx16 %3, %5, 0x1c0\n\t"
                "s_load_dwordx2  %4, %5, 0x200\n\t"
                "s_waitcnt lgkmcnt(0)"
                : "=s"(we), "=s"(wf_), "=s"(wg), "=s"(wh), "=s"(wq)
                : "s"(ua));
            #pragma unroll
            for (int i = 0; i < 8; ++i) {
                v2f wp = (v2f){we[2*i], we[2*i+1]};
                acc = acc + xpk[32 + i] * wp;
            }
            #pragma unroll
            for (int i = 0; i < 8; ++i) {
                v2f wp = (v2f){wf_[2*i], wf_[2*i+1]};
                acc = acc + xpk[40 + i] * wp;
            }
            #pragma unroll
            for (int i = 0; i < 8; ++i) {
                v2f wp = (v2f){wg[2*i], wg[2*i+1]};
                acc = acc + xpk[48 + i] * wp;
            }
            #pragma unroll
            for (int i = 0; i < 8; ++i) {
                v2f wp = (v2f){wh[2*i], wh[2*i+1]};
                acc = acc + xpk[56 + i] * wp;
            }
            s0 = __fadd_rn(__fsub_rn(xsq, __fmul_rn(2.0f, acc.x)), wq.x);
            s1 = __fadd_rn(__fsub_rn(xsq, __fmul_rn(2.0f, acc.y)), wq.y);
        }

        // first-index argmin via u64 key min (scores positive -> bits order-preserving;
        // equal score -> lower index wins: R10/R12-proven ordering)
        int k0 = (p0 + pp) * 2;
        kmin = umin64(kmin, ((u64)__float_as_uint(s0) << 32) | (unsigned)k0);
        kmin = umin64(kmin, ((u64)__float_as_uint(s1) << 32) | (unsigned)(k0 + 1));
    }

    keys[kq][lane] = kmin;
    __syncthreads();

    // -------- 4-way merge + epilogue: wave 0, lane = point (R12-proven ops) --------
    double lsum = 0.0;
    if (tid < 64) {
        u64 kk = keys[0][lane];
        #pragma unroll
        for (int q = 1; q < 4; ++q)
            kk = umin64(kk, keys[q][lane]);
        int bestk = (int)(kk & 0xffffffffu);

        // gather from pair-interleaved row (stride 2), assemble float4 stores
        const float* prow = wtf + (size_t)(bestk >> 1) * PROW + (bestk & 1);
        float4* ov = (float4*)(out + (size_t)point * D_);
        #pragma unroll
        for (int i = 0; i < D_ / 4; ++i) {
            float4 q;
            q.x = prow[2 * (4*i + 0)];
            q.y = prow[2 * (4*i + 1)];
            q.z = prow[2 * (4*i + 2)];
            q.w = prow[2 * (4*i + 3)];
            float e0 = __fsub_rn(q.x, xpk[4*i+0].x), e1 = __fsub_rn(q.y, xpk[4*i+1].x);
            float e2 = __fsub_rn(q.z, xpk[4*i+2].x), e3 = __fsub_rn(q.w, xpk[4*i+3].x);
            float4 o;
            o.x = __fadd_rn(xpk[4*i+0].x, e0); o.y = __fadd_rn(xpk[4*i+1].x, e1);
            o.z = __fadd_rn(xpk[4*i+2].x, e2); o.w = __fadd_rn(xpk[4*i+3].x, e3);
            ov[i] = o;
            lsum += (double)__fmul_rn(e0, e0);
            lsum += (double)__fmul_rn(e1, e1);
            lsum += (double)__fmul_rn(e2, e2);
            lsum += (double)__fmul_rn(e3, e3);
        }
    }
    // wave reduce (waves 1-3 contribute 0), single atomic from tid 0
    #pragma unroll
    for (int off = 32; off >= 1; off >>= 1)
        lsum += __shfl_down(lsum, off);
    if (tid == 0)
        atomicAdd(lacc, lsum);
}

// loss = fl(m + fl(0.25*m)), m = fp32(mean) — R7-verified
__global__ void vq_finalize(const double* __restrict__ lacc, float* __restrict__ out) {
    #pragma clang fp contract(off)
    double m64 = lacc[0] / (double)((size_t)F_ * N_ * D_);
    float m = (float)m64;
    out[0] = __fadd_rn(m, __fmul_rn(0.25f, m));
}

extern "C" void kernel_launch(void* const* d_in, const int* in_sizes, int n_in,
                              void* d_out, int out_size, void* d_ws, size_t ws_size,
                              hipStream_t stream) {
    const float* x = (const float*)d_in[0];   // fp32 [F,N,D]
    const float* w = (const float*)d_in[1];   // fp32 [F,D,K]
    if (in_sizes[0] == F_ * D_ * K_ && in_sizes[1] == F_ * N_ * D_) {
        x = (const float*)d_in[1];
        w = (const float*)d_in[0];
    }
    float* out = (float*)d_out;               // fp32 [F*N*D + 1]

    // ws: wt fp32 [F*KP*PROW] (~2.16 MB) | lacc f64
    float*  wt   = (float*)d_ws;
    double* lacc = (double*)((char*)d_ws + sizeof(float) * (size_t)F_ * KP * PROW);

    hipMemsetAsync(lacc, 0, sizeof(double), stream);
    vq_prep<<<(F_ * K_) / 256, 256, 0, stream>>>(w, wt);
    vq_main<<<(F_ * N_) / 64, 256, 0, stream>>>(x, wt, out, lacc);
    vq_finalize<<<1, 1, 0, stream>>>(lacc, out + (size_t)F_ * N_ * D_);
}